// Round 8
// baseline (12663.248 us; speedup 1.0000x reference)
//
#include <hip/hip_runtime.h>
#include <cmath>

using u16 = unsigned short;
using u32 = unsigned int;
using bf16x8 = __attribute__((ext_vector_type(8))) __bf16;
using f32x4 = __attribute__((ext_vector_type(4))) float;

__device__ __forceinline__ u16 f2bf(float f) {
  union { float f; u32 i; } x; x.f = f;
  u32 r = x.i + 0x7FFFu + ((x.i >> 16) & 1u);
  return (u16)(r >> 16);
}
__device__ __forceinline__ float bf2f(u16 u) {
  union { u32 i; float f; } x; x.i = (u32)u << 16; return x.f;
}
__device__ __forceinline__ float fast_tanh(float x) {
  float e = __expf(2.0f * x);
  return 1.0f - 2.0f / (e + 1.0f);
}

// ---------------- fp32 -> bf16 bulk convert ----------------
__global__ void cvt_bf16(const float* __restrict__ src, u16* __restrict__ dst, int n) {
  int i = (blockIdx.x * 256 + threadIdx.x) * 8;
  if (i + 8 <= n) {
    float4 a = *(const float4*)(src + i), b = *(const float4*)(src + i + 4);
    u16 t[8] = {f2bf(a.x), f2bf(a.y), f2bf(a.z), f2bf(a.w),
                f2bf(b.x), f2bf(b.y), f2bf(b.z), f2bf(b.w)};
    *(uint4*)(dst + i) = *(uint4*)t;
  }
}

// ---------------- barrier slots init (d_ws is poisoned before every launch) ----------------
__global__ void init_bar(u32* __restrict__ bar) {
  if (threadIdx.x < 160) bar[threadIdx.x] = 0u;
}

// ---------------- boxesT[i][b][f] = tanh(inp[b][i]@Wb^T + bb) ----------------
__global__ __launch_bounds__(256) void box_allT(const float* __restrict__ inp,
    const float* __restrict__ Wb, const float* __restrict__ bb, u16* __restrict__ boxesT) {
  int b = blockIdx.x, t = threadIdx.x;
  __shared__ float sin_[64][12];
  for (int idx = t; idx < 768; idx += 256) sin_[idx / 12][idx % 12] = inp[(long)b * 768 + idx];
  int f0 = (t & 127) * 4, hf = t >> 7;
  float w[4][12], bz[4];
#pragma unroll
  for (int r = 0; r < 4; ++r) {
    bz[r] = bb[f0 + r];
#pragma unroll
    for (int q = 0; q < 12; ++q) w[r][q] = Wb[(f0 + r) * 12 + q];
  }
  __syncthreads();
  for (int i = hf; i < 64; i += 2) {
    float a[4] = {bz[0], bz[1], bz[2], bz[3]};
#pragma unroll
    for (int q = 0; q < 12; ++q) {
      float x = sin_[i][q];
#pragma unroll
      for (int r = 0; r < 4; ++r) a[r] += x * w[r][q];
    }
    u16 p[4];
#pragma unroll
    for (int r = 0; r < 4; ++r) p[r] = f2bf(fast_tanh(a[r]));
    *(uint2*)&boxesT[((long)i * 2048 + b) * 512 + f0] = *(uint2*)p;
  }
}

// device-wide barrier: single-use slot per sync point (no reuse -> no ABA).
// 256 blocks co-resident (grid == 256 <= CUs, 1 block/CU fits easily).
__device__ __forceinline__ void grid_bar(u32* __restrict__ bar, int slot, int tid) {
  __syncthreads();
  __threadfence();  // release: flush this block's writes to coherence point
  if (tid == 0) {
    __hip_atomic_fetch_add(&bar[slot], 1u, __ATOMIC_RELEASE, __HIP_MEMORY_SCOPE_AGENT);
    while (__hip_atomic_load(&bar[slot], __ATOMIC_ACQUIRE, __HIP_MEMORY_SCOPE_AGENT) < 256u) {}
  }
  __syncthreads();
  __threadfence();  // acquire: invalidate stale L1/L2 before reading peers' data
}

// ---------------- persistent chain: tiled-GEMM phases with manual grid barrier ----------------
// 256 blocks x 256 threads. Per step t:
//   LEFT: h[2048][1024] = tanh(acc@WL^T (+box@Wr^T | sym-term) + bias), tiles 64m x 128n
//   barrier
//   PROJ: acc[2048][512] = tanh(h@WP^T + bias), tiles 64m x 64f
//   barrier
__global__ __launch_bounds__(256, 1) void chain_pk(
    const u16* __restrict__ boxesT, u16* __restrict__ hBuf, u16* __restrict__ accBuf,
    const u16* __restrict__ WlB, const u16* __restrict__ WrB, const u16* __restrict__ WsB,
    const u16* __restrict__ SlB, const u16* __restrict__ SsB,
    const float* __restrict__ bl, const float* __restrict__ bs,
    const float* __restrict__ sbl, const float* __restrict__ sbr,
    const float* __restrict__ sbs, const float* __restrict__ SrF,
    const float* __restrict__ sym, float* __restrict__ outF,
    u32* __restrict__ bar) {
  __shared__ u16 As[64][72];    // A tile: 64 rows x BK=64 (+pad)
  __shared__ u16 Bs[128][72];   // W tile: up to 128 rows x BK=64 (+pad)

  const int tid = threadIdx.x, lane = tid & 63, w = tid >> 6;
  const int wr = w >> 1, wc = w & 1;
  const int q = lane >> 4, l16 = lane & 15;
  const int bx = blockIdx.x;
  const int mT = (bx & 31) * 64;       // m tile base (both phases)
  const int nL = (bx >> 5) * 128;      // left n tile base
  const int fP = (bx >> 5) * 64;       // proj f tile base
  const int arow = tid >> 2, acol = (tid & 3) * 16;   // As staging map (64x64)
  const int brow = tid >> 1, bcol = (tid & 1) * 32;   // Bs staging map (128x64)

  // pipelined pair for LEFT phase: C += A(64xK=512, stride 512) @ W(128 rows, stride 512)^T
  auto run_left_pair = [&](const u16* Abase, const u16* Wbase, f32x4 (&C)[2][4]) {
    uint4 av[2], bv[4];
    auto stage = [&](int k0) {
      const u16* ap = Abase + (long)(mT + arow) * 512 + k0 + acol;
      av[0] = *(const uint4*)ap;
      av[1] = *(const uint4*)(ap + 8);
      const u16* wp = Wbase + (long)(nL + brow) * 512 + k0 + bcol;
      bv[0] = *(const uint4*)wp;
      bv[1] = *(const uint4*)(wp + 8);
      bv[2] = *(const uint4*)(wp + 16);
      bv[3] = *(const uint4*)(wp + 24);
    };
    stage(0);
    for (int kit = 0; kit < 8; ++kit) {
      __syncthreads();
      *(uint4*)&As[arow][acol] = av[0];
      *(uint4*)&As[arow][acol + 8] = av[1];
      *(uint4*)&Bs[brow][bcol] = bv[0];
      *(uint4*)&Bs[brow][bcol + 8] = bv[1];
      *(uint4*)&Bs[brow][bcol + 16] = bv[2];
      *(uint4*)&Bs[brow][bcol + 24] = bv[3];
      __syncthreads();
      if (kit < 7) stage((kit + 1) * 64);
#pragma unroll
      for (int kk = 0; kk < 2; ++kk) {
        bf16x8 Af[2], Bf[4];
#pragma unroll
        for (int i = 0; i < 2; ++i)
          Af[i] = *(const bf16x8*)&As[wr * 32 + i * 16 + l16][kk * 32 + q * 8];
#pragma unroll
        for (int j = 0; j < 4; ++j)
          Bf[j] = *(const bf16x8*)&Bs[wc * 64 + j * 16 + l16][kk * 32 + q * 8];
#pragma unroll
        for (int i = 0; i < 2; ++i)
#pragma unroll
          for (int j = 0; j < 4; ++j)
            C[i][j] = __builtin_amdgcn_mfma_f32_16x16x32_bf16(Af[i], Bf[j], C[i][j], 0, 0, 0);
      }
    }
  };

  // pipelined PROJ loop: D += h(64xK=1024, stride 1024) @ W(64 rows, stride 1024)^T
  auto run_proj = [&](const u16* Wbase, f32x4 (&D)[2][2]) {
    uint4 av[2], bv[2];
    auto stage = [&](int k0) {
      const u16* ap = hBuf + (long)(mT + arow) * 1024 + k0 + acol;
      av[0] = *(const uint4*)ap;
      av[1] = *(const uint4*)(ap + 8);
      const u16* wp = Wbase + (long)(fP + arow) * 1024 + k0 + acol;
      bv[0] = *(const uint4*)wp;
      bv[1] = *(const uint4*)(wp + 8);
    };
    stage(0);
    for (int kit = 0; kit < 16; ++kit) {
      __syncthreads();
      *(uint4*)&As[arow][acol] = av[0];
      *(uint4*)&As[arow][acol + 8] = av[1];
      *(uint4*)&Bs[arow][acol] = bv[0];
      *(uint4*)&Bs[arow][acol + 8] = bv[1];
      __syncthreads();
      if (kit < 15) stage((kit + 1) * 64);
#pragma unroll
      for (int kk = 0; kk < 2; ++kk) {
        bf16x8 Af[2], Bf[2];
#pragma unroll
        for (int i = 0; i < 2; ++i)
          Af[i] = *(const bf16x8*)&As[wr * 32 + i * 16 + l16][kk * 32 + q * 8];
#pragma unroll
        for (int j = 0; j < 2; ++j)
          Bf[j] = *(const bf16x8*)&Bs[wc * 32 + j * 16 + l16][kk * 32 + q * 8];
#pragma unroll
        for (int i = 0; i < 2; ++i)
#pragma unroll
          for (int j = 0; j < 2; ++j)
            D[i][j] = __builtin_amdgcn_mfma_f32_16x16x32_bf16(Af[i], Bf[j], D[i][j], 0, 0, 0);
      }
    }
  };

  for (int t = 0; t < 79; ++t) {
    const bool symPhase = (t >= 63);
    const int bp = 62 - t;
    const int symp = symPhase ? (15 - (t - 63)) : 0;
    const u16* accSrc = (t == 0) ? (boxesT + (long)63 * 2048 * 512) : accBuf;

    // ---------------- LEFT ----------------
    {
      f32x4 C[2][4];
#pragma unroll
      for (int i = 0; i < 2; ++i)
#pragma unroll
        for (int j = 0; j < 4; ++j) C[i][j] = (f32x4){0.f, 0.f, 0.f, 0.f};

      run_left_pair(accSrc, symPhase ? SlB : WlB, C);
      if (!symPhase) run_left_pair(boxesT + (long)bp * 2048 * 512, WrB, C);

      // epilogue
      float bn[4], srn[4][8];
#pragma unroll
      for (int j = 0; j < 4; ++j) {
        const int n = nL + wc * 64 + j * 16 + l16;
        if (!symPhase) bn[j] = bl[n];
        else {
          bn[j] = sbl[n] + sbr[n];
          *(float4*)&srn[j][0] = *(const float4*)&SrF[(long)n * 8];
          *(float4*)&srn[j][4] = *(const float4*)&SrF[(long)n * 8 + 4];
        }
      }
#pragma unroll
      for (int i = 0; i < 2; ++i) {
#pragma unroll
        for (int r = 0; r < 4; ++r) {
          const int m = mT + wr * 32 + i * 16 + q * 4 + r;
          float sv[8];
          if (symPhase) {
            *(float4*)&sv[0] = *(const float4*)&sym[(long)m * 128 + symp * 8];
            *(float4*)&sv[4] = *(const float4*)&sym[(long)m * 128 + symp * 8 + 4];
          }
#pragma unroll
          for (int j = 0; j < 4; ++j) {
            const int n = nL + wc * 64 + j * 16 + l16;
            float v = C[i][j][r] + bn[j];
            if (symPhase) {
#pragma unroll
              for (int k = 0; k < 8; ++k) v += sv[k] * srn[j][k];
            }
            hBuf[(long)m * 1024 + n] = f2bf(fast_tanh(v));
          }
        }
      }
    }
    grid_bar(bar, 2 * t, tid);

    // ---------------- PROJ ----------------
    {
      f32x4 D[2][2];
#pragma unroll
      for (int i = 0; i < 2; ++i)
#pragma unroll
        for (int j = 0; j < 2; ++j) D[i][j] = (f32x4){0.f, 0.f, 0.f, 0.f};

      run_proj(symPhase ? SsB : WsB, D);

      const float* b2 = symPhase ? sbs : bs;
      const bool last = (t == 78);
      float bn[2];
#pragma unroll
      for (int j = 0; j < 2; ++j) bn[j] = b2[fP + wc * 32 + j * 16 + l16];
#pragma unroll
      for (int i = 0; i < 2; ++i) {
#pragma unroll
        for (int r = 0; r < 4; ++r) {
          const int m = mT + wr * 32 + i * 16 + q * 4 + r;
#pragma unroll
          for (int j = 0; j < 2; ++j) {
            const int f = fP + wc * 32 + j * 16 + l16;
            float a = fast_tanh(D[i][j][r] + bn[j]);
            accBuf[(long)m * 512 + f] = f2bf(a);
            if (last) outF[(long)m * 512 + f] = a;
          }
        }
      }
    }
    if (t < 78) grid_bar(bar, 2 * t + 1, tid);
  }
}

// ================= fallback kernels (small-ws path, proven round-3/4 logic) =================
__global__ __launch_bounds__(256) void box_all_v2(const float* __restrict__ inp,
    const float* __restrict__ Wb, const float* __restrict__ bb, u16* __restrict__ boxes) {
  int b = blockIdx.x, t = threadIdx.x;
  __shared__ float sin_[64][12];
  for (int idx = t; idx < 768; idx += 256) sin_[idx / 12][idx % 12] = inp[(long)b * 768 + idx];
  const int f0 = t * 2;
  float w0[12], w1[12];
#pragma unroll
  for (int q = 0; q < 12; ++q) { w0[q] = Wb[f0 * 12 + q]; w1[q] = Wb[(f0 + 1) * 12 + q]; }
  float b0 = bb[f0], b1 = bb[f0 + 1];
  __syncthreads();
  for (int i = 0; i < 64; ++i) {
    float a0 = b0, a1 = b1;
#pragma unroll
    for (int q = 0; q < 12; ++q) { float x = sin_[i][q]; a0 += x * w0[q]; a1 += x * w1[q]; }
    u32 pk = (u32)f2bf(fast_tanh(a0)) | ((u32)f2bf(fast_tanh(a1)) << 16);
    *(u32*)&boxes[(((long)b * 64 + i) * 512) + f0] = pk;
  }
}

__global__ __launch_bounds__(256) void gemm64(
    const u16* __restrict__ A1, int lda1,
    const u16* __restrict__ W1b, const float* __restrict__ W1f, int K1,
    const u16* __restrict__ A2, int lda2,
    const u16* __restrict__ W2b, const float* __restrict__ W2f, int K2,
    const float* __restrict__ bias,
    const float* __restrict__ symS, const float* __restrict__ Srw, const float* __restrict__ sbr,
    int doTanh, int outMode,
    u16* __restrict__ Cb, float* __restrict__ Cf, int N) {
  __shared__ u16 As[64][72];
  __shared__ u16 Bs[64][72];
  const int tid = threadIdx.x;
  const int lane = tid & 63, w = tid >> 6;
  const int wr = w >> 1, wc = w & 1;
  const int quad = lane >> 4, l16 = lane & 15;
  const int m0 = blockIdx.y * 64, n0 = blockIdx.x * 64;
  const int srow = tid >> 2, scol = (tid & 3) * 16;
  f32x4 acc[2][2];
#pragma unroll
  for (int i = 0; i < 2; ++i)
#pragma unroll
    for (int j = 0; j < 2; ++j) acc[i][j] = (f32x4){0.f, 0.f, 0.f, 0.f};
#pragma unroll
  for (int pair = 0; pair < 2; ++pair) {
    const u16* A = pair ? A2 : A1;
    const u16* Wb_ = pair ? W2b : W1b;
    const float* Wf_ = pair ? W2f : W1f;
    const int lda = pair ? lda2 : lda1;
    const int K = pair ? K2 : K1;
    if (K == 0) continue;
    for (int k0 = 0; k0 < K; k0 += 64) {
      const u16* ap = &A[(long)(m0 + srow) * lda + k0 + scol];
      uint4 av0 = *(const uint4*)ap;
      uint4 av1 = *(const uint4*)(ap + 8);
      uint4 bv0, bv1;
      if (Wb_) {
        const u16* wp = &Wb_[(long)(n0 + srow) * K + k0 + scol];
        bv0 = *(const uint4*)wp;
        bv1 = *(const uint4*)(wp + 8);
      } else {
        const float* wp = &Wf_[(long)(n0 + srow) * K + k0 + scol];
        u16 tv[16];
#pragma unroll
        for (int qq = 0; qq < 16; ++qq) tv[qq] = f2bf(wp[qq]);
        bv0 = ((uint4*)tv)[0];
        bv1 = ((uint4*)tv)[1];
      }
      __syncthreads();
      *(uint4*)&As[srow][scol] = av0;
      *(uint4*)&As[srow][scol + 8] = av1;
      *(uint4*)&Bs[srow][scol] = bv0;
      *(uint4*)&Bs[srow][scol + 8] = bv1;
      __syncthreads();
      bf16x8 af[2][2], bfv[2][2];
#pragma unroll
      for (int kk = 0; kk < 2; ++kk) {
#pragma unroll
        for (int i = 0; i < 2; ++i)
          af[i][kk] = *(const bf16x8*)&As[wr * 32 + i * 16 + l16][kk * 32 + quad * 8];
#pragma unroll
        for (int j = 0; j < 2; ++j)
          bfv[j][kk] = *(const bf16x8*)&Bs[wc * 32 + j * 16 + l16][kk * 32 + quad * 8];
      }
#pragma unroll
      for (int kk = 0; kk < 2; ++kk)
#pragma unroll
        for (int i = 0; i < 2; ++i)
#pragma unroll
          for (int j = 0; j < 2; ++j)
            acc[i][j] = __builtin_amdgcn_mfma_f32_16x16x32_bf16(af[i][kk], bfv[j][kk], acc[i][j], 0, 0, 0);
    }
  }
#pragma unroll
  for (int j = 0; j < 2; ++j) {
    const int n = n0 + wc * 32 + j * 16 + l16;
    float bn = bias ? bias[n] : 0.0f;
    float srn[8];
    if (symS) {
      bn += sbr[n];
#pragma unroll
      for (int qq = 0; qq < 8; ++qq) srn[qq] = Srw[n * 8 + qq];
    }
#pragma unroll
    for (int i = 0; i < 2; ++i) {
#pragma unroll
      for (int r = 0; r < 4; ++r) {
        const int m = m0 + wr * 32 + i * 16 + quad * 4 + r;
        float v = acc[i][j][r] + bn;
        if (symS) {
#pragma unroll
          for (int qq = 0; qq < 8; ++qq) v += symS[(long)m * 128 + qq] * srn[qq];
        }
        if (doTanh) v = fast_tanh(v);
        if (outMode == 0) Cb[(long)m * N + n] = f2bf(v);
        else Cf[(long)m * N + n] = v;
      }
    }
  }
}

extern "C" void kernel_launch(void* const* d_in, const int* in_sizes, int n_in,
                              void* d_out, int out_size, void* d_ws, size_t ws_size,
                              hipStream_t stream) {
  const float* inp = (const float*)d_in[0];
  const float* sym = (const float*)d_in[1];
  const float* Wb  = (const float*)d_in[3];
  const float* bb  = (const float*)d_in[4];
  const float* Wl  = (const float*)d_in[5];
  const float* bl  = (const float*)d_in[6];
  const float* Wr  = (const float*)d_in[7];
  const float* Ws  = (const float*)d_in[8];
  const float* bs  = (const float*)d_in[9];
  const float* Sl  = (const float*)d_in[10];
  const float* sbl = (const float*)d_in[11];
  const float* Sr  = (const float*)d_in[12];
  const float* sbr = (const float*)d_in[13];
  const float* Ss  = (const float*)d_in[14];
  const float* sbs = (const float*)d_in[15];

  const long B = 2048, NB = 64, F = 512, H = 1024;
  const long WE = 524288;
  u16* ws = (u16*)d_ws;
  dim3 blk(256);

  // weights (bf16) + boxesT + hBuf + accBuf + barrier slots (~145.8 MB, proven to fit)
  const size_t needPk =
      ((size_t)5 * WE + (size_t)NB * B * F + (size_t)B * H + (size_t)B * F) * 2 + 1024;

  if (ws_size >= needPk) {
    u16* WlB = ws;
    u16* WrB = WlB + WE;
    u16* WsB = WrB + WE;
    u16* SlB = WsB + WE;
    u16* SsB = SlB + WE;
    u16* boxesT = SsB + WE;            // [64][2048][512]
    u16* hBuf = boxesT + NB * B * F;   // [2048][1024]
    u16* accBuf = hBuf + B * H;        // [2048][512]
    u32* bar = (u32*)(accBuf + B * F); // 160 slots

    cvt_bf16<<<WE / 2048, blk, 0, stream>>>(Wl, WlB, (int)WE);
    cvt_bf16<<<WE / 2048, blk, 0, stream>>>(Wr, WrB, (int)WE);
    cvt_bf16<<<WE / 2048, blk, 0, stream>>>(Ws, WsB, (int)WE);
    cvt_bf16<<<WE / 2048, blk, 0, stream>>>(Sl, SlB, (int)WE);
    cvt_bf16<<<WE / 2048, blk, 0, stream>>>(Ss, SsB, (int)WE);
    init_bar<<<1, 256, 0, stream>>>(bar);
    box_allT<<<B, blk, 0, stream>>>(inp, Wb, bb, boxesT);

    chain_pk<<<256, blk, 0, stream>>>(boxesT, hBuf, accBuf, WlB, WrB, WsB, SlB, SsB,
                                      bl, bs, sbl, sbr, sbs, Sr, sym, (float*)d_out, bar);
  } else {
    // fallback: proven round-3/4 path
    dim3 gH(16, 32), gP(8, 32);
    u16* p = ws;
    u16* boxes = p;
    p += B * NB * F;
    u16* hBuf = p; p += B * H;
    u16* accBuf = p;
    box_all_v2<<<B, blk, 0, stream>>>(inp, Wb, bb, boxes);
    const u16* curA = boxes + 63 * 512;
    int curLda = (int)(NB * F);
    for (int bp = 62; bp >= 0; --bp) {
      gemm64<<<gH, blk, 0, stream>>>(curA, curLda, nullptr, Wl, 512,
                                     boxes + (long)bp * 512, (int)(NB * F), nullptr, Wr, 512,
                                     bl, nullptr, nullptr, nullptr, 1, 0, hBuf, nullptr, 1024);
      gemm64<<<gP, blk, 0, stream>>>(hBuf, 1024, nullptr, Ws, 1024,
                                     nullptr, 0, nullptr, nullptr, 0,
                                     bs, nullptr, nullptr, nullptr, 1, 0, accBuf, nullptr, 512);
      curA = accBuf; curLda = 512;
    }
    for (int symp = 15; symp >= 0; --symp) {
      gemm64<<<gH, blk, 0, stream>>>(accBuf, 512, nullptr, Sl, 512,
                                     nullptr, 0, nullptr, nullptr, 0,
                                     sbl, sym + symp * 8, Sr, sbr, 1, 0, hBuf, nullptr, 1024);
      int om = (symp == 0) ? 1 : 0;
      gemm64<<<gP, blk, 0, stream>>>(hBuf, 1024, nullptr, Ss, 1024,
                                     nullptr, 0, nullptr, nullptr, 0,
                                     sbs, nullptr, nullptr, nullptr, 1, om, accBuf, (float*)d_out, 512);
    }
  }
  (void)in_sizes; (void)n_in; (void)out_size;
}

// Round 9
// 5201.538 us; speedup vs baseline: 2.4345x; 2.4345x over previous
//
#include <hip/hip_runtime.h>
#include <cmath>

using u16 = unsigned short;
using u32 = unsigned int;
using bf16x8 = __attribute__((ext_vector_type(8))) __bf16;
using f32x4 = __attribute__((ext_vector_type(4))) float;

__device__ __forceinline__ u16 f2bf(float f) {
  union { float f; u32 i; } x; x.f = f;
  u32 r = x.i + 0x7FFFu + ((x.i >> 16) & 1u);
  return (u16)(r >> 16);
}
__device__ __forceinline__ float bf2f(u16 u) {
  union { u32 i; float f; } x; x.i = (u32)u << 16; return x.f;
}
__device__ __forceinline__ float fast_tanh(float x) {
  float e = __expf(2.0f * x);
  return 1.0f - 2.0f / (e + 1.0f);
}

// ---------------- fp32 -> bf16 bulk convert ----------------
__global__ void cvt_bf16(const float* __restrict__ src, u16* __restrict__ dst, int n) {
  int i = (blockIdx.x * 256 + threadIdx.x) * 8;
  if (i + 8 <= n) {
    float4 a = *(const float4*)(src + i), b = *(const float4*)(src + i + 4);
    u16 t[8] = {f2bf(a.x), f2bf(a.y), f2bf(a.z), f2bf(a.w),
                f2bf(b.x), f2bf(b.y), f2bf(b.z), f2bf(b.w)};
    *(uint4*)(dst + i) = *(uint4*)t;
  }
}

// ---------------- boxesT[i][b][f] = tanh(inp[b][i]@Wb^T + bb) ----------------
__global__ __launch_bounds__(256) void box_allT(const float* __restrict__ inp,
    const float* __restrict__ Wb, const float* __restrict__ bb, u16* __restrict__ boxesT) {
  int b = blockIdx.x, t = threadIdx.x;
  __shared__ float sin_[64][12];
  for (int idx = t; idx < 768; idx += 256) sin_[idx / 12][idx % 12] = inp[(long)b * 768 + idx];
  int f0 = (t & 127) * 4, hf = t >> 7;
  float w[4][12], bz[4];
#pragma unroll
  for (int r = 0; r < 4; ++r) {
    bz[r] = bb[f0 + r];
#pragma unroll
    for (int q = 0; q < 12; ++q) w[r][q] = Wb[(f0 + r) * 12 + q];
  }
  __syncthreads();
  for (int i = hf; i < 64; i += 2) {
    float a[4] = {bz[0], bz[1], bz[2], bz[3]};
#pragma unroll
    for (int q = 0; q < 12; ++q) {
      float x = sin_[i][q];
#pragma unroll
      for (int r = 0; r < 4; ++r) a[r] += x * w[r][q];
    }
    u16 p[4];
#pragma unroll
    for (int r = 0; r < 4; ++r) p[r] = f2bf(fast_tanh(a[r]));
    *(uint2*)&boxesT[((long)i * 2048 + b) * 512 + f0] = *(uint2*)p;
  }
}

// ---------------- LEFT: h[2048][1024] = tanh(A1@W1^T (+A2@W2^T | sym) + bias) ----------------
// 64m x 128n tiles, grid (8,32) = 256 blocks. K=512 per pass, BK=128 (4 iters/pass).
// A*: bf16 [2048][512]. W*: bf16 [1024][512]. symS = sym + symp*8 (stride 128), SrF [1024][8].
__global__ __launch_bounds__(256) void gemm_left(
    const u16* __restrict__ A1, const u16* __restrict__ A2,
    const u16* __restrict__ W1, const u16* __restrict__ W2,
    const float* __restrict__ bias1,
    const float* __restrict__ symS, const float* __restrict__ SrF, const float* __restrict__ sbr,
    u16* __restrict__ hOut) {
  __shared__ u16 As[64][136];   // +8 pad: 2-way bank alias (free)
  __shared__ u16 Bs[128][136];
  const int tid = threadIdx.x, lane = tid & 63, w = tid >> 6;
  const int wr = w >> 1, wc = w & 1;
  const int q = lane >> 4, l16 = lane & 15;
  const int m0 = blockIdx.y * 64, n0 = blockIdx.x * 128;
  const int arow = tid >> 2, acol = (tid & 3) * 32;
  const int brow = tid >> 1, bcol = (tid & 1) * 64;

  f32x4 C[2][4];
#pragma unroll
  for (int i = 0; i < 2; ++i)
#pragma unroll
    for (int j = 0; j < 4; ++j) C[i][j] = (f32x4){0.f, 0.f, 0.f, 0.f};

  const int nPass = A2 ? 2 : 1;
  for (int pass = 0; pass < nPass; ++pass) {
    const u16* A = pass ? A2 : A1;
    const u16* W = pass ? W2 : W1;
    uint4 av[4], bv[8];
    auto stage = [&](int k0) {
      const u16* ap = A + (long)(m0 + arow) * 512 + k0 + acol;
#pragma unroll
      for (int v = 0; v < 4; ++v) av[v] = *(const uint4*)(ap + v * 8);
      const u16* wp = W + (long)(n0 + brow) * 512 + k0 + bcol;
#pragma unroll
      for (int v = 0; v < 8; ++v) bv[v] = *(const uint4*)(wp + v * 8);
    };
    stage(0);
    for (int kit = 0; kit < 4; ++kit) {
      __syncthreads();
#pragma unroll
      for (int v = 0; v < 4; ++v) *(uint4*)&As[arow][acol + v * 8] = av[v];
#pragma unroll
      for (int v = 0; v < 8; ++v) *(uint4*)&Bs[brow][bcol + v * 8] = bv[v];
      __syncthreads();
      if (kit < 3) stage((kit + 1) * 128);
#pragma unroll
      for (int kk = 0; kk < 4; ++kk) {
        bf16x8 Af[2], Bf[4];
#pragma unroll
        for (int i = 0; i < 2; ++i)
          Af[i] = *(const bf16x8*)&As[wr * 32 + i * 16 + l16][kk * 32 + q * 8];
#pragma unroll
        for (int j = 0; j < 4; ++j)
          Bf[j] = *(const bf16x8*)&Bs[wc * 64 + j * 16 + l16][kk * 32 + q * 8];
#pragma unroll
        for (int i = 0; i < 2; ++i)
#pragma unroll
          for (int j = 0; j < 4; ++j)
            C[i][j] = __builtin_amdgcn_mfma_f32_16x16x32_bf16(Af[i], Bf[j], C[i][j], 0, 0, 0);
      }
    }
  }

  // epilogue
  float bn[4], srn[4][8];
#pragma unroll
  for (int j = 0; j < 4; ++j) {
    const int n = n0 + wc * 64 + j * 16 + l16;
    if (!symS) bn[j] = bias1[n];
    else {
      bn[j] = bias1[n] + sbr[n];
      *(float4*)&srn[j][0] = *(const float4*)&SrF[(long)n * 8];
      *(float4*)&srn[j][4] = *(const float4*)&SrF[(long)n * 8 + 4];
    }
  }
#pragma unroll
  for (int i = 0; i < 2; ++i) {
#pragma unroll
    for (int r = 0; r < 4; ++r) {
      const int m = m0 + wr * 32 + i * 16 + q * 4 + r;
      float sv[8];
      if (symS) {
        *(float4*)&sv[0] = *(const float4*)&symS[(long)m * 128];
        *(float4*)&sv[4] = *(const float4*)&symS[(long)m * 128 + 4];
      }
#pragma unroll
      for (int j = 0; j < 4; ++j) {
        const int n = n0 + wc * 64 + j * 16 + l16;
        float v = C[i][j][r] + bn[j];
        if (symS) {
#pragma unroll
          for (int k = 0; k < 8; ++k) v += sv[k] * srn[j][k];
        }
        hOut[(long)m * 1024 + n] = f2bf(fast_tanh(v));
      }
    }
  }
}

// ---------------- PROJ: acc[2048][512] = tanh(h@W^T + bias) ----------------
// 64m x 64f tiles, grid (8,32) = 256 blocks. K=1024, BK=128 (8 iters).
__global__ __launch_bounds__(256) void gemm_proj(
    const u16* __restrict__ hIn, const u16* __restrict__ W,
    const float* __restrict__ bias, u16* __restrict__ accOut, float* __restrict__ outF) {
  __shared__ u16 As[64][136];
  __shared__ u16 Bs[64][136];
  const int tid = threadIdx.x, lane = tid & 63, w = tid >> 6;
  const int wr = w >> 1, wc = w & 1;
  const int q = lane >> 4, l16 = lane & 15;
  const int m0 = blockIdx.y * 64, f0t = blockIdx.x * 64;
  const int arow = tid >> 2, acol = (tid & 3) * 32;

  f32x4 D[2][2];
#pragma unroll
  for (int i = 0; i < 2; ++i)
#pragma unroll
    for (int j = 0; j < 2; ++j) D[i][j] = (f32x4){0.f, 0.f, 0.f, 0.f};

  uint4 av[4], bv[4];
  auto stage = [&](int k0) {
    const u16* ap = hIn + (long)(m0 + arow) * 1024 + k0 + acol;
#pragma unroll
    for (int v = 0; v < 4; ++v) av[v] = *(const uint4*)(ap + v * 8);
    const u16* wp = W + (long)(f0t + arow) * 1024 + k0 + acol;
#pragma unroll
    for (int v = 0; v < 4; ++v) bv[v] = *(const uint4*)(wp + v * 8);
  };
  stage(0);
  for (int kit = 0; kit < 8; ++kit) {
    __syncthreads();
#pragma unroll
    for (int v = 0; v < 4; ++v) *(uint4*)&As[arow][acol + v * 8] = av[v];
#pragma unroll
    for (int v = 0; v < 4; ++v) *(uint4*)&Bs[arow][acol + v * 8] = bv[v];
    __syncthreads();
    if (kit < 7) stage((kit + 1) * 128);
#pragma unroll
    for (int kk = 0; kk < 4; ++kk) {
      bf16x8 Af[2], Bf[2];
#pragma unroll
      for (int i = 0; i < 2; ++i)
        Af[i] = *(const bf16x8*)&As[wr * 32 + i * 16 + l16][kk * 32 + q * 8];
#pragma unroll
      for (int j = 0; j < 2; ++j)
        Bf[j] = *(const bf16x8*)&Bs[wc * 32 + j * 16 + l16][kk * 32 + q * 8];
#pragma unroll
      for (int i = 0; i < 2; ++i)
#pragma unroll
        for (int j = 0; j < 2; ++j)
          D[i][j] = __builtin_amdgcn_mfma_f32_16x16x32_bf16(Af[i], Bf[j], D[i][j], 0, 0, 0);
    }
  }

  float bn[2];
#pragma unroll
  for (int j = 0; j < 2; ++j) bn[j] = bias[f0t + wc * 32 + j * 16 + l16];
#pragma unroll
  for (int i = 0; i < 2; ++i) {
#pragma unroll
    for (int r = 0; r < 4; ++r) {
      const int m = m0 + wr * 32 + i * 16 + q * 4 + r;
#pragma unroll
      for (int j = 0; j < 2; ++j) {
        const int f = f0t + wc * 32 + j * 16 + l16;
        float a = fast_tanh(D[i][j][r] + bn[j]);
        accOut[(long)m * 512 + f] = f2bf(a);
        if (outF) outF[(long)m * 512 + f] = a;
      }
    }
  }
}

// ================= fallback kernels (small-ws path, proven round-3/4 logic) =================
__global__ __launch_bounds__(256) void box_all_v2(const float* __restrict__ inp,
    const float* __restrict__ Wb, const float* __restrict__ bb, u16* __restrict__ boxes) {
  int b = blockIdx.x, t = threadIdx.x;
  __shared__ float sin_[64][12];
  for (int idx = t; idx < 768; idx += 256) sin_[idx / 12][idx % 12] = inp[(long)b * 768 + idx];
  const int f0 = t * 2;
  float w0[12], w1[12];
#pragma unroll
  for (int q = 0; q < 12; ++q) { w0[q] = Wb[f0 * 12 + q]; w1[q] = Wb[(f0 + 1) * 12 + q]; }
  float b0 = bb[f0], b1 = bb[f0 + 1];
  __syncthreads();
  for (int i = 0; i < 64; ++i) {
    float a0 = b0, a1 = b1;
#pragma unroll
    for (int q = 0; q < 12; ++q) { float x = sin_[i][q]; a0 += x * w0[q]; a1 += x * w1[q]; }
    u32 pk = (u32)f2bf(fast_tanh(a0)) | ((u32)f2bf(fast_tanh(a1)) << 16);
    *(u32*)&boxes[(((long)b * 64 + i) * 512) + f0] = pk;
  }
}

__global__ __launch_bounds__(256) void gemm64(
    const u16* __restrict__ A1, int lda1,
    const float* __restrict__ W1f, int K1,
    const u16* __restrict__ A2, int lda2,
    const float* __restrict__ W2f, int K2,
    const float* __restrict__ bias,
    const float* __restrict__ symS, const float* __restrict__ Srw, const float* __restrict__ sbr,
    int outMode, u16* __restrict__ Cb, float* __restrict__ Cf, int N) {
  __shared__ u16 As[64][72];
  __shared__ u16 Bs[64][72];
  const int tid = threadIdx.x;
  const int lane = tid & 63, w = tid >> 6;
  const int wr = w >> 1, wc = w & 1;
  const int quad = lane >> 4, l16 = lane & 15;
  const int m0 = blockIdx.y * 64, n0 = blockIdx.x * 64;
  const int srow = tid >> 2, scol = (tid & 3) * 16;
  f32x4 acc[2][2];
#pragma unroll
  for (int i = 0; i < 2; ++i)
#pragma unroll
    for (int j = 0; j < 2; ++j) acc[i][j] = (f32x4){0.f, 0.f, 0.f, 0.f};
#pragma unroll
  for (int pair = 0; pair < 2; ++pair) {
    const u16* A = pair ? A2 : A1;
    const float* Wf_ = pair ? W2f : W1f;
    const int lda = pair ? lda2 : lda1;
    const int K = pair ? K2 : K1;
    if (K == 0) continue;
    for (int k0 = 0; k0 < K; k0 += 64) {
      const u16* ap = &A[(long)(m0 + srow) * lda + k0 + scol];
      uint4 av0 = *(const uint4*)ap;
      uint4 av1 = *(const uint4*)(ap + 8);
      const float* wp = &Wf_[(long)(n0 + srow) * K + k0 + scol];
      u16 tv[16];
#pragma unroll
      for (int qq = 0; qq < 16; ++qq) tv[qq] = f2bf(wp[qq]);
      uint4 bv0 = ((uint4*)tv)[0];
      uint4 bv1 = ((uint4*)tv)[1];
      __syncthreads();
      *(uint4*)&As[srow][scol] = av0;
      *(uint4*)&As[srow][scol + 8] = av1;
      *(uint4*)&Bs[srow][scol] = bv0;
      *(uint4*)&Bs[srow][scol + 8] = bv1;
      __syncthreads();
      bf16x8 af[2][2], bfv[2][2];
#pragma unroll
      for (int kk = 0; kk < 2; ++kk) {
#pragma unroll
        for (int i = 0; i < 2; ++i)
          af[i][kk] = *(const bf16x8*)&As[wr * 32 + i * 16 + l16][kk * 32 + quad * 8];
#pragma unroll
        for (int j = 0; j < 2; ++j)
          bfv[j][kk] = *(const bf16x8*)&Bs[wc * 32 + j * 16 + l16][kk * 32 + quad * 8];
      }
#pragma unroll
      for (int kk = 0; kk < 2; ++kk)
#pragma unroll
        for (int i = 0; i < 2; ++i)
#pragma unroll
          for (int j = 0; j < 2; ++j)
            acc[i][j] = __builtin_amdgcn_mfma_f32_16x16x32_bf16(af[i][kk], bfv[j][kk], acc[i][j], 0, 0, 0);
    }
  }
#pragma unroll
  for (int j = 0; j < 2; ++j) {
    const int n = n0 + wc * 32 + j * 16 + l16;
    float bn = bias ? bias[n] : 0.0f;
    float srn[8];
    if (symS) {
      bn += sbr[n];
#pragma unroll
      for (int qq = 0; qq < 8; ++qq) srn[qq] = Srw[n * 8 + qq];
    }
#pragma unroll
    for (int i = 0; i < 2; ++i) {
#pragma unroll
      for (int r = 0; r < 4; ++r) {
        const int m = m0 + wr * 32 + i * 16 + quad * 4 + r;
        float v = acc[i][j][r] + bn;
        if (symS) {
#pragma unroll
          for (int qq = 0; qq < 8; ++qq) v += symS[(long)m * 128 + qq] * srn[qq];
        }
        v = fast_tanh(v);
        if (outMode == 0) Cb[(long)m * N + n] = f2bf(v);
        else Cf[(long)m * N + n] = v;
      }
    }
  }
}

extern "C" void kernel_launch(void* const* d_in, const int* in_sizes, int n_in,
                              void* d_out, int out_size, void* d_ws, size_t ws_size,
                              hipStream_t stream) {
  const float* inp = (const float*)d_in[0];
  const float* sym = (const float*)d_in[1];
  const float* Wb  = (const float*)d_in[3];
  const float* bb  = (const float*)d_in[4];
  const float* Wl  = (const float*)d_in[5];
  const float* bl  = (const float*)d_in[6];
  const float* Wr  = (const float*)d_in[7];
  const float* Ws  = (const float*)d_in[8];
  const float* bs  = (const float*)d_in[9];
  const float* Sl  = (const float*)d_in[10];
  const float* sbl = (const float*)d_in[11];
  const float* Sr  = (const float*)d_in[12];
  const float* sbr = (const float*)d_in[13];
  const float* Ss  = (const float*)d_in[14];
  const float* sbs = (const float*)d_in[15];

  const long B = 2048, NB = 64, F = 512, H = 1024;
  const long WE = 524288;
  u16* ws = (u16*)d_ws;
  dim3 blk(256);

  // bf16 weights + boxesT + h + acc  (~145.8 MB, proven to fit in rounds 3/8)
  const size_t need =
      ((size_t)5 * WE + (size_t)NB * B * F + (size_t)B * H + (size_t)B * F) * 2;

  if (ws_size >= need) {
    u16* WlB = ws;
    u16* WrB = WlB + WE;
    u16* WsB = WrB + WE;
    u16* SlB = WsB + WE;
    u16* SsB = SlB + WE;
    u16* boxesT = SsB + WE;            // [64][2048][512]
    u16* hBuf = boxesT + NB * B * F;   // [2048][1024]
    u16* accBuf = hBuf + B * H;        // [2048][512]

    cvt_bf16<<<WE / 2048, blk, 0, stream>>>(Wl, WlB, (int)WE);
    cvt_bf16<<<WE / 2048, blk, 0, stream>>>(Wr, WrB, (int)WE);
    cvt_bf16<<<WE / 2048, blk, 0, stream>>>(Ws, WsB, (int)WE);
    cvt_bf16<<<WE / 2048, blk, 0, stream>>>(Sl, SlB, (int)WE);
    cvt_bf16<<<WE / 2048, blk, 0, stream>>>(Ss, SsB, (int)WE);
    box_allT<<<B, blk, 0, stream>>>(inp, Wb, bb, boxesT);

    dim3 gL(8, 32), gP(8, 32);
    const u16* curA = boxesT + (long)63 * B * F;
    for (int bp = 62; bp >= 0; --bp) {
      gemm_left<<<gL, blk, 0, stream>>>(curA, boxesT + (long)bp * B * F, WlB, WrB,
                                        bl, nullptr, nullptr, nullptr, hBuf);
      gemm_proj<<<gP, blk, 0, stream>>>(hBuf, WsB, bs, accBuf, nullptr);
      curA = accBuf;
    }
    for (int symp = 15; symp >= 0; --symp) {
      gemm_left<<<gL, blk, 0, stream>>>(accBuf, nullptr, SlB, nullptr,
                                        sbl, sym + symp * 8, Sr, sbr, hBuf);
      float* dstF = (symp == 0) ? (float*)d_out : nullptr;
      gemm_proj<<<gP, blk, 0, stream>>>(hBuf, SsB, sbs, accBuf, dstF);
    }
  } else {
    // fallback: fp32-weight per-step path
    dim3 gH(16, 32), gP(8, 32);
    u16* p = ws;
    u16* boxes = p;
    p += B * NB * F;
    u16* hBuf = p; p += B * H;
    u16* accBuf = p;
    box_all_v2<<<B, blk, 0, stream>>>(inp, Wb, bb, boxes);
    const u16* curA = boxes + 63 * 512;
    int curLda = (int)(NB * F);
    for (int bp = 62; bp >= 0; --bp) {
      gemm64<<<gH, blk, 0, stream>>>(curA, curLda, Wl, 512,
                                     boxes + (long)bp * 512, (int)(NB * F), Wr, 512,
                                     bl, nullptr, nullptr, nullptr, 0, hBuf, nullptr, 1024);
      gemm64<<<gP, blk, 0, stream>>>(hBuf, 1024, Ws, 1024, nullptr, 0, nullptr, 0,
                                     bs, nullptr, nullptr, nullptr, 0, accBuf, nullptr, 512);
      curA = accBuf; curLda = 512;
    }
    for (int symp = 15; symp >= 0; --symp) {
      gemm64<<<gH, blk, 0, stream>>>(accBuf, 512, Sl, 512, nullptr, 0, nullptr, 0,
                                     sbl, sym + symp * 8, Sr, sbr, 0, hBuf, nullptr, 1024);
      int om = (symp == 0) ? 1 : 0;
      gemm64<<<gP, blk, 0, stream>>>(hBuf, 1024, Ss, 1024, nullptr, 0, nullptr, 0,
                                     sbs, nullptr, nullptr, nullptr, om, accBuf, (float*)d_out, 512);
    }
  }
  (void)in_sizes; (void)n_in; (void)out_size;
}